// Round 1
// baseline (237.307 us; speedup 1.0000x reference)
//
#include <hip/hip_runtime.h>
#include <hip/hip_bf16.h>
#include <stdint.h>

#define BATCH 2048
#define FDIM 512
#define CDIM 64
#define BK 64
#define NKT (FDIM / BK)   // 8 K-tiles

typedef unsigned short ushort_t;
typedef __attribute__((ext_vector_type(8))) short short8;
typedef __attribute__((ext_vector_type(4))) float f32x4;

__device__ __forceinline__ ushort_t f2bf(float x) {
    union { float f; uint32_t u; } v; v.f = x;
    uint32_t u = v.u;
    uint32_t r = u + 0x7FFFu + ((u >> 16) & 1u);  // round-to-nearest-even
    return (ushort_t)(r >> 16);
}
__device__ __forceinline__ float bf2f(ushort_t u) {
    union { float f; uint32_t v; } x; x.v = ((uint32_t)u) << 16; return x.f;
}

// ---- fused fp32->bf16 convert: W_proj (8192 blocks), f_feat (512), t_feat (512) ----
__global__ void convert_all_kernel(const float* __restrict__ W, ushort_t* __restrict__ Wb,
                                   const float* __restrict__ f, ushort_t* __restrict__ f16,
                                   const float* __restrict__ t, ushort_t* __restrict__ t16) {
    int blk = blockIdx.x;
    const float* src; ushort_t* dst; int idx;
    if (blk < 8192)      { src = W; dst = Wb;  idx = blk * 256 + threadIdx.x; }
    else if (blk < 8704) { src = f; dst = f16; idx = (blk - 8192) * 256 + threadIdx.x; }
    else                 { src = t; dst = t16; idx = (blk - 8704) * 256 + threadIdx.x; }
    float4 v0 = ((const float4*)src)[idx * 2];
    float4 v1 = ((const float4*)src)[idx * 2 + 1];
    ushort_t p[8] = { f2bf(v0.x), f2bf(v0.y), f2bf(v0.z), f2bf(v0.w),
                      f2bf(v1.x), f2bf(v1.y), f2bf(v1.z), f2bf(v1.w) };
    *(uint4*)&dst[idx * 8] = *(uint4*)p;
}

#define AS3(p) ((__attribute__((address_space(3))) void*)(p))
#define AS1(p) ((const __attribute__((address_space(1))) void*)(p))

// 256x256x(K=64) 8-wave 4-phase-per-K-tile schedule.
// LDS: As/Bs [buf][ksub][256 rows][32 bf16] (64-B rows, chunk-XOR swizzle) + scratch.
// u[b,n] = sum_j f16[b,j]*Wb[n,j]; n = c*512+i; epilogue contracts with t16[b,i].

#define STAGE_A(buf, ksub, kelem)                                                   \
    { _Pragma("unroll")                                                             \
      for (int l = 0; l < 2; l++)                                                   \
        __builtin_amdgcn_global_load_lds(AS1(gA[l] + (kelem) + (ksub) * 32),        \
            AS3(&AsB[buf][ksub][l * 4096 + wave * 512]), 16, 0, 0); }

#define STAGE_B(buf, ksub, kelem)                                                   \
    { _Pragma("unroll")                                                             \
      for (int l = 0; l < 2; l++)                                                   \
        __builtin_amdgcn_global_load_lds(AS1(gB[l] + (kelem) + (ksub) * 32),        \
            AS3(&BsB[buf][ksub][l * 4096 + wave * 512]), 16, 0, 0); }

#define LOADB4(buf, ksub)                                                           \
    { _Pragma("unroll")                                                             \
      for (int ni = 0; ni < 4; ni++)                                                \
        bv[ni] = *(const short8*)&BsB[buf][ksub][b_off[ni]]; }

#define VMW4 asm volatile("s_waitcnt vmcnt(4)" ::: "memory");

#define PHASE(buf, ksub, mibase, EXTRA, STG, VMW)                                   \
    { _Pragma("unroll")                                                             \
      for (int mi = 0; mi < 4; mi++)                                                \
        av[mi] = *(const short8*)&AsB[buf][ksub][a_off[(mibase) + mi]];             \
      EXTRA                                                                         \
      STG                                                                           \
      __builtin_amdgcn_s_barrier();                                                 \
      asm volatile("s_waitcnt lgkmcnt(0)" ::: "memory");                            \
      __builtin_amdgcn_sched_barrier(0);                                            \
      __builtin_amdgcn_s_setprio(1);                                                \
      _Pragma("unroll")                                                             \
      for (int mi = 0; mi < 4; mi++) {                                              \
        _Pragma("unroll")                                                           \
        for (int ni = 0; ni < 4; ni++)                                              \
          acc[(mibase) + mi][ni] = __builtin_amdgcn_mfma_f32_16x16x32_bf16(         \
              av[mi], bv[ni], acc[(mibase) + mi][ni], 0, 0, 0);                     \
      }                                                                             \
      __builtin_amdgcn_s_setprio(0);                                                \
      VMW                                                                           \
      __builtin_amdgcn_s_barrier();                                                 \
      asm volatile("" ::: "memory"); }

#define DO_KTILE(buf, nk)                                                           \
    PHASE(buf, 0, 0, LOADB4(buf, 0), STAGE_A((buf) ^ 1, 0, nk), )                   \
    PHASE(buf, 0, 4, , STAGE_B((buf) ^ 1, 0, nk), VMW4)                             \
    PHASE(buf, 1, 0, LOADB4(buf, 1), STAGE_A((buf) ^ 1, 1, nk), )                   \
    PHASE(buf, 1, 4, , STAGE_B((buf) ^ 1, 1, nk), VMW4)

__launch_bounds__(512, 2)
__global__ void gemm_fused_kernel(const ushort_t* __restrict__ f16,
                                  const ushort_t* __restrict__ Wb,
                                  const ushort_t* __restrict__ t16,
                                  float* __restrict__ part) {
    // 64 KiB + 64 KiB + 4 KiB = 132 KiB (gfx950 LDS = 160 KiB/CU, 1 block/CU)
    __shared__ ushort_t AsB[2][2][256 * 32];
    __shared__ ushort_t BsB[2][2][256 * 32];
    __shared__ float scratch[256 * 4];

    const int tid  = threadIdx.x;
    const int wave = tid >> 6;
    const int lane = tid & 63;
    const int l15  = lane & 15;
    const int lg   = lane >> 4;
    const int wm   = wave >> 2;    // 0..1  (M half)
    const int wn   = wave & 3;     // 0..3  (N quarter)

    // XCD-chunked bijective swizzle: 1024 blocks, 128 contiguous per XCD.
    // Each XCD covers 16 n-panels (4 MiB of Wb -> fits its private L2) x all 8 m-blocks.
    const int swz = (blockIdx.x & 7) * 128 + (blockIdx.x >> 3);
    const int by  = swz >> 3;      // 0..127 n-chunk
    const int bx  = swz & 7;       // 0..7   m-chunk
    const int b0  = bx * 256;
    const int n0  = by * 256;

    // staging addresses: slot s = l*512+tid; phys (row, chunk); global chunk XOR-swizzled
    const ushort_t* gA[2];
    const ushort_t* gB[2];
    #pragma unroll
    for (int l = 0; l < 2; l++) {
        int s   = l * 512 + tid;
        int row = s >> 2;
        int cg  = (s & 3) ^ ((row >> 1) & 3);
        gA[l] = f16 + (size_t)(b0 + row) * FDIM + cg * 8;
        // B row permute: phys row q holds global n_local = (q&~63) | ((q&15)<<2) | ((q>>4)&3)
        int bq = (row & ~63) | ((row & 15) << 2) | ((row >> 4) & 3);
        gB[l] = Wb + (size_t)(n0 + bq) * FDIM + cg * 8;
    }

    // fragment ds_read element offsets (chunk XOR depends only on l15 here)
    int a_off[8], b_off[4];
    const int cx = (lg ^ ((l15 >> 1) & 3)) * 8;
    #pragma unroll
    for (int mi = 0; mi < 8; mi++) {
        int r = wm * 128 + mi * 16 + l15;
        a_off[mi] = r * 32 + cx;
    }
    #pragma unroll
    for (int ni = 0; ni < 4; ni++) {
        int q = wn * 64 + ni * 16 + l15;
        b_off[ni] = q * 32 + cx;
    }

    f32x4 acc[8][4];
    #pragma unroll
    for (int mi = 0; mi < 8; mi++)
        #pragma unroll
        for (int ni = 0; ni < 4; ni++)
            acc[mi][ni] = (f32x4){0.f, 0.f, 0.f, 0.f};

    short8 av[4], bv[4];

    // prologue: stage K-tile 0 fully, drain once
    STAGE_A(0, 0, 0)
    STAGE_B(0, 0, 0)
    STAGE_A(0, 1, 0)
    STAGE_B(0, 1, 0)
    __syncthreads();

    // main loop: 2 K-tiles per iteration, counted vmcnt(4) twice per K-tile, never 0
    for (int kt2 = 0; kt2 < 4; kt2++) {
        const int nk1 = (kt2 * 2 + 1) * BK;
        const int nk2 = (kt2 < 3) ? (kt2 * 2 + 2) * BK : 0;  // wrapped (harmless) tail prefetch
        DO_KTILE(0, nk1)
        DO_KTILE(1, nk2)
    }

    // epilogue: contract with t16. B row permute makes frag ni, col l15 -> n_local = l15*4+ni,
    // so the 4 ni t-factors are one ushort4 load.
    const int c     = n0 >> 9;
    const int half  = (n0 >> 8) & 1;
    const int ibase = (n0 & 511) + wn * 64 + l15 * 4;
    #pragma unroll
    for (int mi = 0; mi < 8; mi++) {
        const int row_blk = wm * 128 + mi * 16 + lg * 4;
        #pragma unroll
        for (int r = 0; r < 4; r++) {
            ushort4 tv = *(const ushort4*)&t16[(size_t)(b0 + row_blk + r) * FDIM + ibase];
            float sv = acc[mi][0][r] * bf2f(tv.x) + acc[mi][1][r] * bf2f(tv.y)
                     + acc[mi][2][r] * bf2f(tv.z) + acc[mi][3][r] * bf2f(tv.w);
            sv += __shfl_xor(sv, 1, 64);
            sv += __shfl_xor(sv, 2, 64);
            sv += __shfl_xor(sv, 4, 64);
            sv += __shfl_xor(sv, 8, 64);
            if (l15 == 0) scratch[(row_blk + r) * 4 + wn] = sv;
        }
    }
    __syncthreads();
    if (tid < 256) {
        float4 s4 = *(const float4*)&scratch[tid * 4];
        part[((size_t)(b0 + tid) * CDIM + c) * 2 + half] = s4.x + s4.y + s4.z + s4.w;
    }
}

// ---- MLP head: part[b][c][2] halves -> relu(proj) -> relu(W1) -> W2 ----
__global__ void mlp_kernel(const float* __restrict__ part,
                           const float* __restrict__ b_proj,
                           const float* __restrict__ W1, const float* __restrict__ b1,
                           const float* __restrict__ W2, const float* __restrict__ b2,
                           float* __restrict__ out) {
    __shared__ float h[8][64];
    const int tid = threadIdx.x;
    const int bl  = tid >> 5;        // 0..7
    const int o   = tid & 31;
    const int b   = blockIdx.x * 8 + bl;

    #pragma unroll
    for (int c = o; c < 64; c += 32) {
        float2 v = *(const float2*)&part[((size_t)b * 64 + c) * 2];
        float sv = v.x + v.y + b_proj[c];
        h[bl][c] = sv > 0.f ? sv : 0.f;
    }
    __syncthreads();

    float sv = b1[o];
    #pragma unroll
    for (int c = 0; c < 64; c++) sv += h[bl][c] * W1[o * 64 + c];
    float v = (sv > 0.f ? sv : 0.f) * W2[o];
    v += __shfl_xor(v, 1, 32);
    v += __shfl_xor(v, 2, 32);
    v += __shfl_xor(v, 4, 32);
    v += __shfl_xor(v, 8, 32);
    v += __shfl_xor(v, 16, 32);
    if (o == 0) out[b] = v + b2[0];
}

extern "C" void kernel_launch(void* const* d_in, const int* in_sizes, int n_in,
                              void* d_out, int out_size, void* d_ws, size_t ws_size,
                              hipStream_t stream) {
    const float* t_feat = (const float*)d_in[0];
    const float* f_feat = (const float*)d_in[1];
    const float* W_proj = (const float*)d_in[2];
    const float* b_proj = (const float*)d_in[3];
    const float* W1     = (const float*)d_in[4];
    const float* b1     = (const float*)d_in[5];
    const float* W2     = (const float*)d_in[6];
    const float* b2     = (const float*)d_in[7];
    float* out = (float*)d_out;

    uint8_t* ws = (uint8_t*)d_ws;
    ushort_t* Wb   = (ushort_t*)(ws);                          // 32 MiB
    ushort_t* f16  = (ushort_t*)(ws + 33554432);               // 2 MiB
    ushort_t* t16  = (ushort_t*)(ws + 33554432 + 2097152);     // 2 MiB
    float*    part = (float*)(ws + 33554432 + 2 * 2097152);    // 1 MiB used

    convert_all_kernel<<<dim3(9216), dim3(256), 0, stream>>>(W_proj, Wb, f_feat, f16, t_feat, t16);

    gemm_fused_kernel<<<dim3(1024), dim3(512), 0, stream>>>(f16, Wb, t16, part);

    mlp_kernel<<<dim3(BATCH / 8), dim3(256), 0, stream>>>(part, b_proj, W1, b1, W2, b2, out);
}